// Round 5
// baseline (550.218 us; speedup 1.0000x reference)
//
#include <hip/hip_runtime.h>
#include <math.h>

// Problem constants
#define T_SEQ 2048
#define D_MODEL 3072
#define NQ 16
#define NKV 8
#define HD 256
#define NHEADS_TOT 32          // 16 q + 8 k + 8 v projection "slots"
#define QKV_COLS 8192          // 32 * 256
#define SOFT_CAP 50.0f
#define WINDOW 1024
#define K_MASK -2.3819763e38f

typedef __attribute__((ext_vector_type(8))) short bf16x8;
typedef __attribute__((ext_vector_type(4))) float f32x4;

__device__ __forceinline__ unsigned short f2bf(float f) {
    union { float f; unsigned u; } v; v.f = f;
    unsigned r = (v.u + 0x7fff + ((v.u >> 16) & 1)) >> 16;
    return (unsigned short)r;
}
__device__ __forceinline__ float bf2f(unsigned short u) {
    union { unsigned u; float f; } v; v.u = ((unsigned)u) << 16;
    return v.f;
}

__device__ __forceinline__ void gl_lds16(const unsigned short* g, unsigned short* l) {
    __builtin_amdgcn_global_load_lds(
        (const __attribute__((address_space(1))) void*)g,
        (__attribute__((address_space(3))) void*)l, 16, 0, 0);
}

// ---------------- convert f32 -> bf16 (flat) ----------------
__global__ __launch_bounds__(256) void k_convert(const float* __restrict__ src,
                                                 unsigned short* __restrict__ dst, int n4) {
    int i = blockIdx.x * 256 + threadIdx.x;
    if (i >= n4) return;
    float4 v = ((const float4*)src)[i];
    ushort4 o;
    o.x = f2bf(v.x); o.y = f2bf(v.y); o.z = f2bf(v.z); o.w = f2bf(v.w);
    ((ushort4*)dst)[i] = o;
}

// ---------------- batched transpose+convert: (batch,R,C) f32 -> (batch,C,R) bf16 ----------------
__global__ __launch_bounds__(256) void k_transpose_bf16(const float* __restrict__ src,
                                                        unsigned short* __restrict__ dst,
                                                        int R, int C) {
    __shared__ float tile[32][33];
    int b = blockIdx.z;
    src += (size_t)b * R * C;
    dst += (size_t)b * R * C;
    int c0 = blockIdx.x * 32, r0 = blockIdx.y * 32;
    int tx = threadIdx.x, ty = threadIdx.y;   // 32 x 8
    #pragma unroll
    for (int i = ty; i < 32; i += 8)
        tile[i][tx] = src[(size_t)(r0 + i) * C + c0 + tx];
    __syncthreads();
    #pragma unroll
    for (int i = ty; i < 32; i += 8)
        dst[(size_t)(c0 + i) * R + r0 + tx] = f2bf(tile[tx][i]);
}

// ---------------- bf16 transpose: vh (8, T, H) -> vT (8, H, T) ----------------
__global__ __launch_bounds__(256) void k_transpose_v(const unsigned short* __restrict__ src,
                                                     unsigned short* __restrict__ dst) {
    __shared__ unsigned short tile[32][34];
    int kk = blockIdx.z;
    src += (size_t)kk * T_SEQ * HD;
    dst += (size_t)kk * HD * T_SEQ;
    int h0 = blockIdx.x * 32, t0 = blockIdx.y * 32;
    int tx = threadIdx.x, ty = threadIdx.y;   // 32 x 8
    #pragma unroll
    for (int i = ty; i < 32; i += 8)
        tile[i][tx] = src[(size_t)(t0 + i) * HD + h0 + tx];
    __syncthreads();
    #pragma unroll
    for (int i = ty; i < 32; i += 8)
        dst[(size_t)(h0 + i) * T_SEQ + t0 + tx] = tile[tx][i];
}

// ---------------- RoPE trig table: (T, 128) float2 {sin, cos} ----------------
// Same instruction sequence as the previous in-kernel computation -> bit-identical.
__global__ __launch_bounds__(128) void k_trig(const int* __restrict__ spos,
                                              float2* __restrict__ tbl) {
    int t = blockIdx.x, hh = threadIdx.x;
    float fr = (float)hh * (1.0f / 128.0f);
    float ts = __expf(fr * 9.210340371976184f);   // 10000^fr
    float ang = (float)spos[t] / ts;
    float2 sc;
    sc.x = __sinf(ang);
    sc.y = __cosf(ang);
    tbl[(size_t)t * 128 + hh] = sc;
}

// ---------------- NT GEMM: C[M,N] = A[M,K] * BT[N,K]^T   (bf16 in, f32 acc) ----------------
// 128x128 block tile, BK=64, 4 waves each 64x64. XCD-aware 1-D grid remap.
template <int OUT_BF16>
__global__ __launch_bounds__(256) void k_gemm_nt(const unsigned short* __restrict__ A,
                                                 const unsigned short* __restrict__ BT,
                                                 void* __restrict__ Cout,
                                                 int M, int N, int Kd) {
    __shared__ unsigned short As[128 * 64];
    __shared__ unsigned short Bs[128 * 64];
    const int tid = threadIdx.x;
    const int wave = tid >> 6, lane = tid & 63;
    const int col = lane & 15, quad = lane >> 4;
    const int wr = wave >> 1, wc = wave & 1;

    const int gx = M >> 7;
    int p = blockIdx.x;
    int xcd = p & 7, q = p >> 3;
    int i_t = q % gx, jj = q / gx;
    int j_t = jj * 8 + xcd;
    const int m0 = i_t * 128, n0 = j_t * 128;

    const int sub = wave & 1, isB = wave >> 1;
    const unsigned short* srcBase = isB ? (BT + (size_t)(n0 + sub * 64) * Kd)
                                        : (A + (size_t)(m0 + sub * 64) * Kd);
    unsigned short* ldsBase = (isB ? Bs : As) + sub * 64 * 64;
    const int lrow = lane >> 3, lchk = lane & 7;
    int soff[8];
    #pragma unroll
    for (int s = 0; s < 8; s++) {
        int r = s * 8 + lrow;
        soff[s] = r * Kd + ((lchk ^ (r & 7)) * 8);
    }

    f32x4 acc[4][4];
    #pragma unroll
    for (int i = 0; i < 4; i++)
        #pragma unroll
        for (int j = 0; j < 4; j++)
            acc[i][j] = (f32x4){0.f, 0.f, 0.f, 0.f};

    const int sw = col & 7;

    for (int k0 = 0; k0 < Kd; k0 += 64) {
        #pragma unroll
        for (int s = 0; s < 8; s++)
            gl_lds16(srcBase + soff[s] + k0, ldsBase + s * 512);
        __syncthreads();

        #pragma unroll
        for (int kk = 0; kk < 2; kk++) {
            bf16x8 af[4], bfr[4];
            const int chko = ((kk * 4 + quad) ^ sw) * 8;
            #pragma unroll
            for (int i = 0; i < 4; i++)
                af[i] = *(const bf16x8*)&As[(wr * 64 + i * 16 + col) * 64 + chko];
            #pragma unroll
            for (int j = 0; j < 4; j++)
                bfr[j] = *(const bf16x8*)&Bs[(wc * 64 + j * 16 + col) * 64 + chko];
            #pragma unroll
            for (int i = 0; i < 4; i++)
                #pragma unroll
                for (int j = 0; j < 4; j++)
                    acc[i][j] = __builtin_amdgcn_mfma_f32_16x16x32_bf16(af[i], bfr[j], acc[i][j], 0, 0, 0);
        }
        __syncthreads();
    }

    #pragma unroll
    for (int i = 0; i < 4; i++) {
        int row = m0 + wr * 64 + i * 16 + quad * 4;
        #pragma unroll
        for (int j = 0; j < 4; j++) {
            int c = n0 + wc * 64 + j * 16 + col;
            #pragma unroll
            for (int r = 0; r < 4; r++) {
                float v = acc[i][j][r];
                if (OUT_BF16)
                    ((unsigned short*)Cout)[(size_t)(row + r) * N + c] = f2bf(v);
                else
                    ((float*)Cout)[(size_t)(row + r) * N + c] = v;
            }
        }
    }
}

// ---------------- RMS-norm (+scale) + RoPE (trig from table) ----------------
__global__ __launch_bounds__(256) void k_norm_rope(const unsigned short* __restrict__ qkv,
                                                   const float2* __restrict__ trig,
                                                   const float* __restrict__ qscale,
                                                   const float* __restrict__ kscale,
                                                   unsigned short* __restrict__ qh,
                                                   unsigned short* __restrict__ kh,
                                                   unsigned short* __restrict__ vh) {
    const int t = blockIdx.x, slot = blockIdx.y, h = threadIdx.x;
    float val = bf2f(qkv[(size_t)t * QKV_COLS + slot * HD + h]);
    float ss = val * val;
    #pragma unroll
    for (int m = 1; m < 64; m <<= 1) ss += __shfl_xor(ss, m, 64);
    __shared__ float wsum[4];
    __shared__ float ybuf[256];
    if ((h & 63) == 0) wsum[h >> 6] = ss;
    __syncthreads();
    float tot = wsum[0] + wsum[1] + wsum[2] + wsum[3];
    float y = val * rsqrtf(tot * (1.0f / 256.0f) + 1e-6f);
    if (slot < 16) y *= (1.0f + qscale[h]);
    else if (slot < 24) y *= (1.0f + kscale[h]);

    if (slot < 24) {
        ybuf[h] = y;
        __syncthreads();
        int hh = h & 127;
        float2 sc = trig[(size_t)t * 128 + hh];
        float sn = sc.x, cs = sc.y;
        float other = ybuf[(h < 128) ? (h + 128) : (h - 128)];
        float outv = (h < 128) ? (y * cs - other * sn) : (y * cs + other * sn);
        if (slot < 16)
            qh[((size_t)slot * T_SEQ + t) * HD + h] = f2bf(outv);
        else
            kh[((size_t)(slot - 16) * T_SEQ + t) * HD + h] = f2bf(outv);
    } else {
        vh[((size_t)(slot - 24) * T_SEQ + t) * HD + h] = f2bf(y);
    }
}

// ---------------- flash attention (R3-proven 32-s-tile version) ----------------
// Block: 256 thr = 4 waves. blockIdx.x = kv head (8), blockIdx.y = 32-row t tile (64).
// K/V tiles staged in LDS once per 32-col step, shared by all 4 waves.
// Softmax with fixed m=0 (logits bounded +-50 by softcap).
__global__ __launch_bounds__(256) void k_attn(const unsigned short* __restrict__ qh,
                                              const unsigned short* __restrict__ kh,
                                              const unsigned short* __restrict__ vT,
                                              unsigned short* __restrict__ enc) {
    __shared__ unsigned short Ks[32 * 256];   // [s][k], 16B granules XOR-swizzled by (s&7)
    __shared__ unsigned short Vs[256 * 32];   // [h][s], 16B granules XOR-swizzled by (h&3)
    __shared__ unsigned short Pl[4][16 * 40]; // per-wave P round-trip

    const int tid = threadIdx.x;
    const int wave = tid >> 6, lane = tid & 63;
    const int col = lane & 15, quad = lane >> 4;
    const int kk = blockIdx.x;
    const int t0b = blockIdx.y * 32;
    const int headSel = wave & 1, rowSel = wave >> 1;
    const int n = kk * 2 + headSel;
    const int tw = t0b + rowSel * 16;

    const unsigned short* qp = qh + ((size_t)n * T_SEQ + tw) * HD;
    const unsigned short* kp = kh + (size_t)kk * T_SEQ * HD;
    const unsigned short* vp = vT + (size_t)kk * HD * T_SEQ;

    bf16x8 qf[8];
    #pragma unroll
    for (int c = 0; c < 8; c++)
        qf[c] = *(const bf16x8*)(qp + (size_t)col * HD + c * 32 + quad * 8);

    int preK[4], preV[4], ldsKo[4], ldsVo[4];
    #pragma unroll
    for (int i = 0; i < 4; i++) {
        int krow = 2 * (wave * 4 + i) + (lane >> 5);
        int kpos = lane & 31;
        preK[i] = krow * HD + ((kpos ^ (krow & 7)) * 8);
        ldsKo[i] = (wave * 4 + i) * 512;
        int vh2 = (wave * 4 + i) * 16 + (lane >> 2);
        int vpp = lane & 3;
        preV[i] = vh2 * T_SEQ + ((vpp ^ (vh2 & 3)) * 8);
        ldsVo[i] = (wave * 4 + i) * 512;
    }

    f32x4 o[16];
    #pragma unroll
    for (int h = 0; h < 16; h++) o[h] = (f32x4){0.f, 0.f, 0.f, 0.f};
    float lsum[4] = {0.f, 0.f, 0.f, 0.f};

    int s_begin = t0b - (WINDOW - 1);
    if (s_begin < 0) s_begin = 0;
    s_begin &= ~31;
    const int s_end = t0b + 32;

    for (int s0 = s_begin; s0 < s_end; s0 += 32) {
        #pragma unroll
        for (int i = 0; i < 4; i++)
            gl_lds16(kp + (size_t)s0 * HD + preK[i], &Ks[ldsKo[i]]);
        #pragma unroll
        for (int i = 0; i < 4; i++)
            gl_lds16(vp + (size_t)s0 + preV[i], &Vs[ldsVo[i]]);
        __syncthreads();

        f32x4 S0 = (f32x4){0.f, 0.f, 0.f, 0.f};
        f32x4 S1 = (f32x4){0.f, 0.f, 0.f, 0.f};
        #pragma unroll
        for (int c = 0; c < 8; c++) {
            bf16x8 kf = *(const bf16x8*)&Ks[(size_t)col * HD + (((c * 4 + quad) ^ (col & 7)) * 8)];
            S0 = __builtin_amdgcn_mfma_f32_16x16x32_bf16(qf[c], kf, S0, 0, 0, 0);
        }
        #pragma unroll
        for (int c = 0; c < 8; c++) {
            bf16x8 kf = *(const bf16x8*)&Ks[(size_t)(16 + col) * HD + (((c * 4 + quad) ^ (col & 7)) * 8)];
            S1 = __builtin_amdgcn_mfma_f32_16x16x32_bf16(qf[c], kf, S1, 0, 0, 0);
        }

        #pragma unroll
        for (int r = 0; r < 4; r++) {
            int t = tw + quad * 4 + r;
            int sA = s0 + col, sB = sA + 16;
            bool vA = (sA <= t) && (sA >= t - (WINDOW - 1));
            bool vB = (sB <= t) && (sB >= t - (WINDOW - 1));
            float eA = __expf(S0[r] * (2.0f / SOFT_CAP));
            float eB = __expf(S1[r] * (2.0f / SOFT_CAP));
            float rA = __builtin_amdgcn_rcpf(eA + 1.0f);
            float rB = __builtin_amdgcn_rcpf(eB + 1.0f);
            float pA = __expf(SOFT_CAP - 2.0f * SOFT_CAP * rA);
            float pB = __expf(SOFT_CAP - 2.0f * SOFT_CAP * rB);
            pA = vA ? pA : 0.0f;
            pB = vB ? pB : 0.0f;
            lsum[r] += pA + pB;
            Pl[wave][(quad * 4 + r) * 40 + col] = f2bf(pA);
            Pl[wave][(quad * 4 + r) * 40 + 16 + col] = f2bf(pB);
        }

        bf16x8 pf = *(const bf16x8*)&Pl[wave][col * 40 + quad * 8];

        #pragma unroll
        for (int ht = 0; ht < 16; ht++) {
            int h = ht * 16 + col;
            bf16x8 vf = *(const bf16x8*)&Vs[(size_t)h * 32 + ((quad ^ (h & 3)) * 8)];
            o[ht] = __builtin_amdgcn_mfma_f32_16x16x32_bf16(pf, vf, o[ht], 0, 0, 0);
        }
        __syncthreads();
    }

    #pragma unroll
    for (int r = 0; r < 4; r++) {
        #pragma unroll
        for (int m = 1; m < 16; m <<= 1)
            lsum[r] += __shfl_xor(lsum[r], m, 16);
        lsum[r] = 1.0f / lsum[r];
    }
    #pragma unroll
    for (int ht = 0; ht < 16; ht++) {
        #pragma unroll
        for (int r = 0; r < 4; r++) {
            int t = tw + quad * 4 + r;
            enc[(size_t)t * (NQ * HD) + n * HD + ht * 16 + col] = f2bf(o[ht][r] * lsum[r]);
        }
    }
}

extern "C" void kernel_launch(void* const* d_in, const int* in_sizes, int n_in,
                              void* d_out, int out_size, void* d_ws, size_t ws_size,
                              hipStream_t stream) {
    const float* x       = (const float*)d_in[0];
    const int*   spos    = (const int*)d_in[1];
    const float* w_q     = (const float*)d_in[3];
    const float* w_kv    = (const float*)d_in[4];
    const float* w_out   = (const float*)d_in[5];
    const float* q_scale = (const float*)d_in[6];
    const float* k_scale = (const float*)d_in[7];
    float* out = (float*)d_out;

    char* ws = (char*)d_ws;
    unsigned short* xb     = (unsigned short*)(ws + 0);          // 2048x3072 bf16 (dead after gemm1)
    unsigned short* vh     = (unsigned short*)(ws + 0);          // 8x2048x256 bf16 (reuses xb[0:8.4MB])
    float2*         trig   = (float2*)(ws + 8388608);            // 2048x128 float2 (reuses xb tail)
    unsigned short* wT     = (unsigned short*)(ws + 12582912);   // 8192x3072 bf16
    unsigned short* wToutb = (unsigned short*)(ws + 12582912);   // 3072x4096 bf16 (reuse)
    unsigned short* encb   = (unsigned short*)(ws + 37748736);   // 2048x4096 bf16 (reuse)
    unsigned short* qkv    = (unsigned short*)(ws + 62914560);   // 2048x8192 bf16
    unsigned short* qh     = (unsigned short*)(ws + 96468992);   // 16x2048x256 bf16
    unsigned short* kh     = (unsigned short*)(ws + 113246208);  // 8x2048x256 bf16
    unsigned short* vT     = (unsigned short*)(ws + 121634816);  // 8x256x2048 bf16

    k_convert<<<dim3((T_SEQ * D_MODEL / 4 + 255) / 256), dim3(256), 0, stream>>>(
        x, xb, T_SEQ * D_MODEL / 4);
    k_transpose_bf16<<<dim3(HD / 32, D_MODEL / 32, NQ), dim3(32, 8), 0, stream>>>(
        w_q, wT, D_MODEL, HD);
    k_transpose_bf16<<<dim3(HD / 32, D_MODEL / 32, 16), dim3(32, 8), 0, stream>>>(
        w_kv, wT + (size_t)4096 * D_MODEL, D_MODEL, HD);
    k_gemm_nt<1><<<dim3((T_SEQ / 128) * (QKV_COLS / 128)), dim3(256), 0, stream>>>(
        xb, wT, qkv, T_SEQ, QKV_COLS, D_MODEL);
    // trig table lives in xb's tail — launched after gemm1 (stream-ordered)
    k_trig<<<dim3(T_SEQ), dim3(128), 0, stream>>>(spos, trig);
    k_transpose_bf16<<<dim3(D_MODEL / 32, 4096 / 32, 1), dim3(32, 8), 0, stream>>>(
        w_out, wToutb, 4096, D_MODEL);
    k_norm_rope<<<dim3(T_SEQ, NHEADS_TOT), dim3(256), 0, stream>>>(
        qkv, trig, q_scale, k_scale, qh, kh, vh);
    k_transpose_v<<<dim3(HD / 32, T_SEQ / 32, NKV), dim3(32, 8), 0, stream>>>(vh, vT);
    k_attn<<<dim3(NKV, T_SEQ / 32), dim3(256), 0, stream>>>(qh, kh, vT, encb);
    k_gemm_nt<0><<<dim3((T_SEQ / 128) * (D_MODEL / 128)), dim3(256), 0, stream>>>(
        encb, wToutb, out, T_SEQ, D_MODEL, NQ * HD);
}

// Round 6
// 517.883 us; speedup vs baseline: 1.0624x; 1.0624x over previous
//
#include <hip/hip_runtime.h>
#include <math.h>

// Problem constants
#define T_SEQ 2048
#define D_MODEL 3072
#define NQ 16
#define NKV 8
#define HD 256
#define NHEADS_TOT 32          // 16 q + 8 k + 8 v projection "slots"
#define QKV_COLS 8192          // 32 * 256
#define SOFT_CAP 50.0f
#define WINDOW 1024
#define K_MASK -2.3819763e38f

typedef __attribute__((ext_vector_type(8))) short bf16x8;
typedef __attribute__((ext_vector_type(4))) float f32x4;

__device__ __forceinline__ unsigned short f2bf(float f) {
    union { float f; unsigned u; } v; v.f = f;
    unsigned r = (v.u + 0x7fff + ((v.u >> 16) & 1)) >> 16;
    return (unsigned short)r;
}
__device__ __forceinline__ float bf2f(unsigned short u) {
    union { unsigned u; float f; } v; v.u = ((unsigned)u) << 16;
    return v.f;
}

__device__ __forceinline__ void gl_lds16(const unsigned short* g, unsigned short* l) {
    __builtin_amdgcn_global_load_lds(
        (const __attribute__((address_space(1))) void*)g,
        (__attribute__((address_space(3))) void*)l, 16, 0, 0);
}

// ---------------- convert f32 -> bf16 (flat) ----------------
__global__ __launch_bounds__(256) void k_convert(const float* __restrict__ src,
                                                 unsigned short* __restrict__ dst, int n4) {
    int i = blockIdx.x * 256 + threadIdx.x;
    if (i >= n4) return;
    float4 v = ((const float4*)src)[i];
    ushort4 o;
    o.x = f2bf(v.x); o.y = f2bf(v.y); o.z = f2bf(v.z); o.w = f2bf(v.w);
    ((ushort4*)dst)[i] = o;
}

// ---------------- batched transpose+convert: (batch,R,C) f32 -> (batch,C,R) bf16 ----------------
__global__ __launch_bounds__(256) void k_transpose_bf16(const float* __restrict__ src,
                                                        unsigned short* __restrict__ dst,
                                                        int R, int C) {
    __shared__ float tile[32][33];
    int b = blockIdx.z;
    src += (size_t)b * R * C;
    dst += (size_t)b * R * C;
    int c0 = blockIdx.x * 32, r0 = blockIdx.y * 32;
    int tx = threadIdx.x, ty = threadIdx.y;   // 32 x 8
    #pragma unroll
    for (int i = ty; i < 32; i += 8)
        tile[i][tx] = src[(size_t)(r0 + i) * C + c0 + tx];
    __syncthreads();
    #pragma unroll
    for (int i = ty; i < 32; i += 8)
        dst[(size_t)(c0 + i) * R + r0 + tx] = f2bf(tile[tx][i]);
}

// ---------------- bf16 transpose: vh (8, T, H) -> vT (8, H, T) ----------------
__global__ __launch_bounds__(256) void k_transpose_v(const unsigned short* __restrict__ src,
                                                     unsigned short* __restrict__ dst) {
    __shared__ unsigned short tile[32][34];
    int kk = blockIdx.z;
    src += (size_t)kk * T_SEQ * HD;
    dst += (size_t)kk * HD * T_SEQ;
    int h0 = blockIdx.x * 32, t0 = blockIdx.y * 32;
    int tx = threadIdx.x, ty = threadIdx.y;   // 32 x 8
    #pragma unroll
    for (int i = ty; i < 32; i += 8)
        tile[i][tx] = src[(size_t)(t0 + i) * HD + h0 + tx];
    __syncthreads();
    #pragma unroll
    for (int i = ty; i < 32; i += 8)
        dst[(size_t)(h0 + i) * T_SEQ + t0 + tx] = tile[tx][i];
}

// ---------------- RoPE trig table: (T, 128) float2 {sin, cos} ----------------
__global__ __launch_bounds__(128) void k_trig(const int* __restrict__ spos,
                                              float2* __restrict__ tbl) {
    int t = blockIdx.x, hh = threadIdx.x;
    float fr = (float)hh * (1.0f / 128.0f);
    float ts = __expf(fr * 9.210340371976184f);   // 10000^fr
    float ang = (float)spos[t] / ts;
    float2 sc;
    sc.x = __sinf(ang);
    sc.y = __cosf(ang);
    tbl[(size_t)t * 128 + hh] = sc;
}

// ---------------- NT GEMM (gemm1): C[M,N] = A[M,K] * BT[N,K]^T, 128x128, BK=64 ----------------
template <int OUT_BF16>
__global__ __launch_bounds__(256) void k_gemm_nt(const unsigned short* __restrict__ A,
                                                 const unsigned short* __restrict__ BT,
                                                 void* __restrict__ Cout,
                                                 int M, int N, int Kd) {
    __shared__ unsigned short As[128 * 64];
    __shared__ unsigned short Bs[128 * 64];
    const int tid = threadIdx.x;
    const int wave = tid >> 6, lane = tid & 63;
    const int col = lane & 15, quad = lane >> 4;
    const int wr = wave >> 1, wc = wave & 1;

    const int gx = M >> 7;
    int p = blockIdx.x;
    int xcd = p & 7, q = p >> 3;
    int i_t = q % gx, jj = q / gx;
    int j_t = jj * 8 + xcd;
    const int m0 = i_t * 128, n0 = j_t * 128;

    const int sub = wave & 1, isB = wave >> 1;
    const unsigned short* srcBase = isB ? (BT + (size_t)(n0 + sub * 64) * Kd)
                                        : (A + (size_t)(m0 + sub * 64) * Kd);
    unsigned short* ldsBase = (isB ? Bs : As) + sub * 64 * 64;
    const int lrow = lane >> 3, lchk = lane & 7;
    int soff[8];
    #pragma unroll
    for (int s = 0; s < 8; s++) {
        int r = s * 8 + lrow;
        soff[s] = r * Kd + ((lchk ^ (r & 7)) * 8);
    }

    f32x4 acc[4][4];
    #pragma unroll
    for (int i = 0; i < 4; i++)
        #pragma unroll
        for (int j = 0; j < 4; j++)
            acc[i][j] = (f32x4){0.f, 0.f, 0.f, 0.f};

    const int sw = col & 7;

    for (int k0 = 0; k0 < Kd; k0 += 64) {
        #pragma unroll
        for (int s = 0; s < 8; s++)
            gl_lds16(srcBase + soff[s] + k0, ldsBase + s * 512);
        __syncthreads();

        #pragma unroll
        for (int kk = 0; kk < 2; kk++) {
            bf16x8 af[4], bfr[4];
            const int chko = ((kk * 4 + quad) ^ sw) * 8;
            #pragma unroll
            for (int i = 0; i < 4; i++)
                af[i] = *(const bf16x8*)&As[(wr * 64 + i * 16 + col) * 64 + chko];
            #pragma unroll
            for (int j = 0; j < 4; j++)
                bfr[j] = *(const bf16x8*)&Bs[(wc * 64 + j * 16 + col) * 64 + chko];
            #pragma unroll
            for (int i = 0; i < 4; i++)
                #pragma unroll
                for (int j = 0; j < 4; j++)
                    acc[i][j] = __builtin_amdgcn_mfma_f32_16x16x32_bf16(af[i], bfr[j], acc[i][j], 0, 0, 0);
        }
        __syncthreads();
    }

    #pragma unroll
    for (int i = 0; i < 4; i++) {
        int row = m0 + wr * 64 + i * 16 + quad * 4;
        #pragma unroll
        for (int j = 0; j < 4; j++) {
            int c = n0 + wc * 64 + j * 16 + col;
            #pragma unroll
            for (int r = 0; r < 4; r++) {
                float v = acc[i][j][r];
                if (OUT_BF16)
                    ((unsigned short*)Cout)[(size_t)(row + r) * N + c] = f2bf(v);
                else
                    ((float*)Cout)[(size_t)(row + r) * N + c] = v;
            }
        }
    }
}

// ---------------- gemm2: 128x64 tile, BK=64, 768 blocks (3/CU), f32 out ----------------
// Same per-element k-order as the 128x128 version -> bit-identical output.
__global__ __launch_bounds__(256) void k_gemm2(const unsigned short* __restrict__ A,
                                               const unsigned short* __restrict__ BT,
                                               float* __restrict__ C,
                                               int M, int N, int Kd) {
    __shared__ unsigned short As[128 * 64];
    __shared__ unsigned short Bs[64 * 64];
    const int tid = threadIdx.x;
    const int wave = tid >> 6, lane = tid & 63;
    const int col = lane & 15, quad = lane >> 4;

    const int gx = M >> 7;                 // 16
    int p = blockIdx.x;                    // 768 blocks
    int xcd = p & 7, q = p >> 3;
    int i_t = q % gx, jj = q / gx;
    int j_t = jj * 8 + xcd;                // [0, 48)
    const int m0 = i_t * 128, n0 = j_t * 64;

    const int lrow = lane >> 3, lchk = lane & 7;
    int soffA[4], soffB[2];
    #pragma unroll
    for (int s = 0; s < 4; s++) {
        int r = (wave * 4 + s) * 8 + lrow;
        soffA[s] = r * Kd + ((lchk ^ (r & 7)) * 8);
    }
    #pragma unroll
    for (int s = 0; s < 2; s++) {
        int r = (wave * 2 + s) * 8 + lrow;
        soffB[s] = r * Kd + ((lchk ^ (r & 7)) * 8);
    }
    const unsigned short* Ab = A + (size_t)m0 * Kd;
    const unsigned short* Bb = BT + (size_t)n0 * Kd;

    f32x4 acc[2][4];
    #pragma unroll
    for (int i = 0; i < 2; i++)
        #pragma unroll
        for (int j = 0; j < 4; j++)
            acc[i][j] = (f32x4){0.f, 0.f, 0.f, 0.f};

    const int sw = col & 7;

    for (int k0 = 0; k0 < Kd; k0 += 64) {
        #pragma unroll
        for (int s = 0; s < 4; s++)
            gl_lds16(Ab + soffA[s] + k0, &As[(wave * 4 + s) * 512]);
        #pragma unroll
        for (int s = 0; s < 2; s++)
            gl_lds16(Bb + soffB[s] + k0, &Bs[(wave * 2 + s) * 512]);
        __syncthreads();

        #pragma unroll
        for (int kk = 0; kk < 2; kk++) {
            const int chko = ((kk * 4 + quad) ^ sw) * 8;
            bf16x8 af[2], bfr[4];
            #pragma unroll
            for (int i = 0; i < 2; i++)
                af[i] = *(const bf16x8*)&As[(wave * 32 + i * 16 + col) * 64 + chko];
            #pragma unroll
            for (int j = 0; j < 4; j++)
                bfr[j] = *(const bf16x8*)&Bs[(j * 16 + col) * 64 + chko];
            #pragma unroll
            for (int i = 0; i < 2; i++)
                #pragma unroll
                for (int j = 0; j < 4; j++)
                    acc[i][j] = __builtin_amdgcn_mfma_f32_16x16x32_bf16(af[i], bfr[j], acc[i][j], 0, 0, 0);
        }
        __syncthreads();
    }

    #pragma unroll
    for (int i = 0; i < 2; i++) {
        int row = m0 + wave * 32 + i * 16 + quad * 4;
        #pragma unroll
        for (int j = 0; j < 4; j++) {
            int c = n0 + j * 16 + col;
            #pragma unroll
            for (int r = 0; r < 4; r++)
                C[(size_t)(row + r) * N + c] = acc[i][j][r];
        }
    }
}

// ---------------- RMS-norm (+scale) + RoPE: 4 slots per block ----------------
// Block (t, y) handles slots {y, y+8, y+16, y+24}: 2 q + 1 k + 1 v.
// Per-slot math (shuffle tree, wsum order, rsqrt, trig values) identical to the
// one-slot version -> bit-identical outputs. 8192 blocks instead of 65536.
__global__ __launch_bounds__(256) void k_norm_rope(const unsigned short* __restrict__ qkv,
                                                   const float2* __restrict__ trig,
                                                   const float* __restrict__ qscale,
                                                   const float* __restrict__ kscale,
                                                   unsigned short* __restrict__ qh,
                                                   unsigned short* __restrict__ kh,
                                                   unsigned short* __restrict__ vh) {
    const int t = blockIdx.x, y = blockIdx.y, h = threadIdx.x;
    __shared__ float wsum[4][4];
    __shared__ float ybuf[3][256];

    float val[4];
    #pragma unroll
    for (int g = 0; g < 4; g++)
        val[g] = bf2f(qkv[(size_t)t * QKV_COLS + (y + g * 8) * HD + h]);

    float ssg[4];
    #pragma unroll
    for (int g = 0; g < 4; g++) {
        float ss = val[g] * val[g];
        #pragma unroll
        for (int m = 1; m < 64; m <<= 1) ss += __shfl_xor(ss, m, 64);
        ssg[g] = ss;
    }
    if ((h & 63) == 0) {
        #pragma unroll
        for (int g = 0; g < 4; g++) wsum[g][h >> 6] = ssg[g];
    }
    __syncthreads();

    float2 sc = trig[(size_t)t * 128 + (h & 127)];
    float qs = 1.0f + qscale[h], ks = 1.0f + kscale[h];

    float yv[4];
    #pragma unroll
    for (int g = 0; g < 4; g++) {
        float tot = wsum[g][0] + wsum[g][1] + wsum[g][2] + wsum[g][3];
        float yy = val[g] * rsqrtf(tot * (1.0f / 256.0f) + 1e-6f);
        if (g < 2) yy *= qs;
        else if (g == 2) yy *= ks;
        yv[g] = yy;
        if (g < 3) ybuf[g][h] = yy;
    }
    __syncthreads();

    #pragma unroll
    for (int g = 0; g < 3; g++) {
        float other = ybuf[g][(h < 128) ? (h + 128) : (h - 128)];
        float outv = (h < 128) ? (yv[g] * sc.y - other * sc.x)
                               : (yv[g] * sc.y + other * sc.x);
        int slot = y + g * 8;
        if (slot < 16)
            qh[((size_t)slot * T_SEQ + t) * HD + h] = f2bf(outv);
        else
            kh[((size_t)(slot - 16) * T_SEQ + t) * HD + h] = f2bf(outv);
    }
    vh[((size_t)y * T_SEQ + t) * HD + h] = f2bf(yv[3]);
}

// ---------------- flash attention (32-s-tile, R3-proven) ----------------
__global__ __launch_bounds__(256) void k_attn(const unsigned short* __restrict__ qh,
                                              const unsigned short* __restrict__ kh,
                                              const unsigned short* __restrict__ vT,
                                              unsigned short* __restrict__ enc) {
    __shared__ unsigned short Ks[32 * 256];
    __shared__ unsigned short Vs[256 * 32];
    __shared__ unsigned short Pl[4][16 * 40];

    const int tid = threadIdx.x;
    const int wave = tid >> 6, lane = tid & 63;
    const int col = lane & 15, quad = lane >> 4;
    const int kk = blockIdx.x;
    const int t0b = blockIdx.y * 32;
    const int headSel = wave & 1, rowSel = wave >> 1;
    const int n = kk * 2 + headSel;
    const int tw = t0b + rowSel * 16;

    const unsigned short* qp = qh + ((size_t)n * T_SEQ + tw) * HD;
    const unsigned short* kp = kh + (size_t)kk * T_SEQ * HD;
    const unsigned short* vp = vT + (size_t)kk * HD * T_SEQ;

    bf16x8 qf[8];
    #pragma unroll
    for (int c = 0; c < 8; c++)
        qf[c] = *(const bf16x8*)(qp + (size_t)col * HD + c * 32 + quad * 8);

    int preK[4], preV[4], ldsKo[4], ldsVo[4];
    #pragma unroll
    for (int i = 0; i < 4; i++) {
        int krow = 2 * (wave * 4 + i) + (lane >> 5);
        int kpos = lane & 31;
        preK[i] = krow * HD + ((kpos ^ (krow & 7)) * 8);
        ldsKo[i] = (wave * 4 + i) * 512;
        int vh2 = (wave * 4 + i) * 16 + (lane >> 2);
        int vpp = lane & 3;
        preV[i] = vh2 * T_SEQ + ((vpp ^ (vh2 & 3)) * 8);
        ldsVo[i] = (wave * 4 + i) * 512;
    }

    f32x4 o[16];
    #pragma unroll
    for (int h = 0; h < 16; h++) o[h] = (f32x4){0.f, 0.f, 0.f, 0.f};
    float lsum[4] = {0.f, 0.f, 0.f, 0.f};

    int s_begin = t0b - (WINDOW - 1);
    if (s_begin < 0) s_begin = 0;
    s_begin &= ~31;
    const int s_end = t0b + 32;

    for (int s0 = s_begin; s0 < s_end; s0 += 32) {
        #pragma unroll
        for (int i = 0; i < 4; i++)
            gl_lds16(kp + (size_t)s0 * HD + preK[i], &Ks[ldsKo[i]]);
        #pragma unroll
        for (int i = 0; i < 4; i++)
            gl_lds16(vp + (size_t)s0 + preV[i], &Vs[ldsVo[i]]);
        __syncthreads();

        f32x4 S0 = (f32x4){0.f, 0.f, 0.f, 0.f};
        f32x4 S1 = (f32x4){0.f, 0.f, 0.f, 0.f};
        #pragma unroll
        for (int c = 0; c < 8; c++) {
            bf16x8 kf = *(const bf16x8*)&Ks[(size_t)col * HD + (((c * 4 + quad) ^ (col & 7)) * 8)];
            S0 = __builtin_amdgcn_mfma_f32_16x16x32_bf16(qf[c], kf, S0, 0, 0, 0);
        }
        #pragma unroll
        for (int c = 0; c < 8; c++) {
            bf16x8 kf = *(const bf16x8*)&Ks[(size_t)(16 + col) * HD + (((c * 4 + quad) ^ (col & 7)) * 8)];
            S1 = __builtin_amdgcn_mfma_f32_16x16x32_bf16(qf[c], kf, S1, 0, 0, 0);
        }

        #pragma unroll
        for (int r = 0; r < 4; r++) {
            int t = tw + quad * 4 + r;
            int sA = s0 + col, sB = sA + 16;
            bool vA = (sA <= t) && (sA >= t - (WINDOW - 1));
            bool vB = (sB <= t) && (sB >= t - (WINDOW - 1));
            float eA = __expf(S0[r] * (2.0f / SOFT_CAP));
            float eB = __expf(S1[r] * (2.0f / SOFT_CAP));
            float rA = __builtin_amdgcn_rcpf(eA + 1.0f);
            float rB = __builtin_amdgcn_rcpf(eB + 1.0f);
            float pA = __expf(SOFT_CAP - 2.0f * SOFT_CAP * rA);
            float pB = __expf(SOFT_CAP - 2.0f * SOFT_CAP * rB);
            pA = vA ? pA : 0.0f;
            pB = vB ? pB : 0.0f;
            lsum[r] += pA + pB;
            Pl[wave][(quad * 4 + r) * 40 + col] = f2bf(pA);
            Pl[wave][(quad * 4 + r) * 40 + 16 + col] = f2bf(pB);
        }

        bf16x8 pf = *(const bf16x8*)&Pl[wave][col * 40 + quad * 8];

        #pragma unroll
        for (int ht = 0; ht < 16; ht++) {
            int h = ht * 16 + col;
            bf16x8 vf = *(const bf16x8*)&Vs[(size_t)h * 32 + ((quad ^ (h & 3)) * 8)];
            o[ht] = __builtin_amdgcn_mfma_f32_16x16x32_bf16(pf, vf, o[ht], 0, 0, 0);
        }
        __syncthreads();
    }

    #pragma unroll
    for (int r = 0; r < 4; r++) {
        #pragma unroll
        for (int m = 1; m < 16; m <<= 1)
            lsum[r] += __shfl_xor(lsum[r], m, 16);
        lsum[r] = 1.0f / lsum[r];
    }
    #pragma unroll
    for (int ht = 0; ht < 16; ht++) {
        #pragma unroll
        for (int r = 0; r < 4; r++) {
            int t = tw + quad * 4 + r;
            enc[(size_t)t * (NQ * HD) + n * HD + ht * 16 + col] = f2bf(o[ht][r] * lsum[r]);
        }
    }
}

extern "C" void kernel_launch(void* const* d_in, const int* in_sizes, int n_in,
                              void* d_out, int out_size, void* d_ws, size_t ws_size,
                              hipStream_t stream) {
    const float* x       = (const float*)d_in[0];
    const int*   spos    = (const int*)d_in[1];
    const float* w_q     = (const float*)d_in[3];
    const float* w_kv    = (const float*)d_in[4];
    const float* w_out   = (const float*)d_in[5];
    const float* q_scale = (const float*)d_in[6];
    const float* k_scale = (const float*)d_in[7];
    float* out = (float*)d_out;

    char* ws = (char*)d_ws;
    unsigned short* xb     = (unsigned short*)(ws + 0);          // 2048x3072 bf16 (dead after gemm1)
    unsigned short* vh     = (unsigned short*)(ws + 0);          // 8x2048x256 bf16 (reuses xb[0:8.4MB])
    float2*         trig   = (float2*)(ws + 8388608);            // 2048x128 float2 (reuses xb tail)
    unsigned short* wT     = (unsigned short*)(ws + 12582912);   // 8192x3072 bf16
    unsigned short* wToutb = (unsigned short*)(ws + 12582912);   // 3072x4096 bf16 (reuse)
    unsigned short* encb   = (unsigned short*)(ws + 37748736);   // 2048x4096 bf16 (reuse)
    unsigned short* qkv    = (unsigned short*)(ws + 62914560);   // 2048x8192 bf16
    unsigned short* qh     = (unsigned short*)(ws + 96468992);   // 16x2048x256 bf16
    unsigned short* kh     = (unsigned short*)(ws + 113246208);  // 8x2048x256 bf16
    unsigned short* vT     = (unsigned short*)(ws + 121634816);  // 8x256x2048 bf16

    k_convert<<<dim3((T_SEQ * D_MODEL / 4 + 255) / 256), dim3(256), 0, stream>>>(
        x, xb, T_SEQ * D_MODEL / 4);
    k_transpose_bf16<<<dim3(HD / 32, D_MODEL / 32, NQ), dim3(32, 8), 0, stream>>>(
        w_q, wT, D_MODEL, HD);
    k_transpose_bf16<<<dim3(HD / 32, D_MODEL / 32, 16), dim3(32, 8), 0, stream>>>(
        w_kv, wT + (size_t)4096 * D_MODEL, D_MODEL, HD);
    k_gemm_nt<1><<<dim3((T_SEQ / 128) * (QKV_COLS / 128)), dim3(256), 0, stream>>>(
        xb, wT, qkv, T_SEQ, QKV_COLS, D_MODEL);
    k_trig<<<dim3(T_SEQ), dim3(128), 0, stream>>>(spos, trig);
    k_transpose_bf16<<<dim3(D_MODEL / 32, 4096 / 32, 1), dim3(32, 8), 0, stream>>>(
        w_out, wToutb, 4096, D_MODEL);
    k_norm_rope<<<dim3(T_SEQ, 8), dim3(256), 0, stream>>>(
        qkv, trig, q_scale, k_scale, qh, kh, vh);
    k_transpose_v<<<dim3(HD / 32, T_SEQ / 32, NKV), dim3(32, 8), 0, stream>>>(vh, vT);
    k_attn<<<dim3(NKV, T_SEQ / 32), dim3(256), 0, stream>>>(qh, kh, vT, encb);
    k_gemm2<<<dim3((T_SEQ / 128) * (D_MODEL / 64)), dim3(256), 0, stream>>>(
        encb, wToutb, out, T_SEQ, D_MODEL, NQ * HD);
}

// Round 7
// 485.280 us; speedup vs baseline: 1.1338x; 1.0672x over previous
//
#include <hip/hip_runtime.h>
#include <math.h>

// Problem constants
#define T_SEQ 2048
#define D_MODEL 3072
#define NQ 16
#define NKV 8
#define HD 256
#define NHEADS_TOT 32
#define QKV_COLS 8192
#define SOFT_CAP 50.0f
#define WINDOW 1024
#define K_MASK -2.3819763e38f

typedef __attribute__((ext_vector_type(8))) short bf16x8;
typedef __attribute__((ext_vector_type(4))) float f32x4;

__device__ __forceinline__ unsigned short f2bf(float f) {
    union { float f; unsigned u; } v; v.f = f;
    unsigned r = (v.u + 0x7fff + ((v.u >> 16) & 1)) >> 16;
    return (unsigned short)r;
}
__device__ __forceinline__ float bf2f(unsigned short u) {
    union { unsigned u; float f; } v; v.u = ((unsigned)u) << 16;
    return v.f;
}

__device__ __forceinline__ void gl_lds16(const unsigned short* g, unsigned short* l) {
    __builtin_amdgcn_global_load_lds(
        (const __attribute__((address_space(1))) void*)g,
        (__attribute__((address_space(3))) void*)l, 16, 0, 0);
}

// ---------------- convert f32 -> bf16 (flat) ----------------
__global__ __launch_bounds__(256) void k_convert(const float* __restrict__ src,
                                                 unsigned short* __restrict__ dst, int n4) {
    int i = blockIdx.x * 256 + threadIdx.x;
    if (i >= n4) return;
    float4 v = ((const float4*)src)[i];
    ushort4 o;
    o.x = f2bf(v.x); o.y = f2bf(v.y); o.z = f2bf(v.z); o.w = f2bf(v.w);
    ((ushort4*)dst)[i] = o;
}

// ---------------- batched transpose+convert: (batch,R,C) f32 -> (batch,C,R) bf16 ----------------
__global__ __launch_bounds__(256) void k_transpose_bf16(const float* __restrict__ src,
                                                        unsigned short* __restrict__ dst,
                                                        int R, int C) {
    __shared__ float tile[32][33];
    int b = blockIdx.z;
    src += (size_t)b * R * C;
    dst += (size_t)b * R * C;
    int c0 = blockIdx.x * 32, r0 = blockIdx.y * 32;
    int tx = threadIdx.x, ty = threadIdx.y;   // 32 x 8
    #pragma unroll
    for (int i = ty; i < 32; i += 8)
        tile[i][tx] = src[(size_t)(r0 + i) * C + c0 + tx];
    __syncthreads();
    #pragma unroll
    for (int i = ty; i < 32; i += 8)
        dst[(size_t)(c0 + i) * R + r0 + tx] = f2bf(tile[tx][i]);
}

// ---------------- bf16 transpose: vh (8, T, H) -> vT (8, H, T) ----------------
__global__ __launch_bounds__(256) void k_transpose_v(const unsigned short* __restrict__ src,
                                                     unsigned short* __restrict__ dst) {
    __shared__ unsigned short tile[32][34];
    int kk = blockIdx.z;
    src += (size_t)kk * T_SEQ * HD;
    dst += (size_t)kk * HD * T_SEQ;
    int h0 = blockIdx.x * 32, t0 = blockIdx.y * 32;
    int tx = threadIdx.x, ty = threadIdx.y;   // 32 x 8
    #pragma unroll
    for (int i = ty; i < 32; i += 8)
        tile[i][tx] = src[(size_t)(t0 + i) * HD + h0 + tx];
    __syncthreads();
    #pragma unroll
    for (int i = ty; i < 32; i += 8)
        dst[(size_t)(h0 + i) * T_SEQ + t0 + tx] = tile[tx][i];
}

// ---------------- RoPE trig table: (T, 128) float2 {sin, cos} ----------------
__global__ __launch_bounds__(128) void k_trig(const int* __restrict__ spos,
                                              float2* __restrict__ tbl) {
    int t = blockIdx.x, hh = threadIdx.x;
    float fr = (float)hh * (1.0f / 128.0f);
    float ts = __expf(fr * 9.210340371976184f);   // 10000^fr
    float ang = (float)spos[t] / ts;
    float2 sc;
    sc.x = __sinf(ang);
    sc.y = __cosf(ang);
    tbl[(size_t)t * 128 + hh] = sc;
}

// ---------------- gemm1: C[M,N]=A*BT^T, 128x256 tile, BK=64, ONE round (512 blk @ 2/CU) ----------
// 4 waves, each computes 64x128 (acc 4x8 tiles = 128 AGPR). __launch_bounds__(256,2) caps regs at 256.
// Same per-element k-order as 128x128/BK64 version -> bit-identical bf16 output.
__global__ __launch_bounds__(256, 2) void k_gemm1(const unsigned short* __restrict__ A,
                                                  const unsigned short* __restrict__ BT,
                                                  unsigned short* __restrict__ C,
                                                  int M, int N, int Kd) {
    __shared__ unsigned short As[128 * 64];   // 16 KB
    __shared__ unsigned short Bs[256 * 64];   // 32 KB
    const int tid = threadIdx.x;
    const int wave = tid >> 6, lane = tid & 63;
    const int col = lane & 15, quad = lane >> 4;
    const int wr = wave & 1, wc = wave >> 1;

    int p = blockIdx.x;                 // 512 blocks
    int xcd = p & 7, q = p >> 3;        // q in [0,64)
    int i_t = q & 15, jj = q >> 4;      // i in [0,16), jj in [0,4)
    const int m0 = i_t * 128, n0 = (jj * 8 + xcd) * 256;

    const int lrow = lane >> 3, lchk = lane & 7;
    int soffA[4], soffB[8];
    #pragma unroll
    for (int s = 0; s < 4; s++) {
        int r = wave * 32 + s * 8 + lrow;
        soffA[s] = r * Kd + ((lchk ^ (r & 7)) * 8);
    }
    #pragma unroll
    for (int s = 0; s < 8; s++) {
        int r = wave * 64 + s * 8 + lrow;
        soffB[s] = r * Kd + ((lchk ^ (r & 7)) * 8);
    }
    const unsigned short* Ab = A + (size_t)m0 * Kd;
    const unsigned short* Bb = BT + (size_t)n0 * Kd;

    f32x4 acc[4][8];
    #pragma unroll
    for (int i = 0; i < 4; i++)
        #pragma unroll
        for (int j = 0; j < 8; j++)
            acc[i][j] = (f32x4){0.f, 0.f, 0.f, 0.f};

    const int sw = col & 7;

    for (int k0 = 0; k0 < Kd; k0 += 64) {
        #pragma unroll
        for (int s = 0; s < 4; s++)
            gl_lds16(Ab + soffA[s] + k0, &As[(wave * 32 + s * 8) * 64]);
        #pragma unroll
        for (int s = 0; s < 8; s++)
            gl_lds16(Bb + soffB[s] + k0, &Bs[(wave * 64 + s * 8) * 64]);
        __syncthreads();

        #pragma unroll
        for (int kk = 0; kk < 2; kk++) {
            const int chko = ((kk * 4 + quad) ^ sw) * 8;
            bf16x8 af[4];
            #pragma unroll
            for (int i = 0; i < 4; i++)
                af[i] = *(const bf16x8*)&As[(wr * 64 + i * 16 + col) * 64 + chko];
            #pragma unroll
            for (int j = 0; j < 8; j++) {
                bf16x8 bfr = *(const bf16x8*)&Bs[(wc * 128 + j * 16 + col) * 64 + chko];
                #pragma unroll
                for (int i = 0; i < 4; i++)
                    acc[i][j] = __builtin_amdgcn_mfma_f32_16x16x32_bf16(af[i], bfr, acc[i][j], 0, 0, 0);
            }
        }
        __syncthreads();
    }

    #pragma unroll
    for (int i = 0; i < 4; i++) {
        int row = m0 + wr * 64 + i * 16 + quad * 4;
        #pragma unroll
        for (int j = 0; j < 8; j++) {
            int c = n0 + wc * 128 + j * 16 + col;
            #pragma unroll
            for (int r = 0; r < 4; r++)
                C[(size_t)(row + r) * N + c] = f2bf(acc[i][j][r]);
        }
    }
}

// ---------------- gemm2: 128x64 tile, BK=128 (32 barriers), 768 blocks, f32 out ----------------
// Ascending k-order per element -> bit-identical to BK=64 version.
__global__ __launch_bounds__(256) void k_gemm2(const unsigned short* __restrict__ A,
                                               const unsigned short* __restrict__ BT,
                                               float* __restrict__ C,
                                               int M, int N, int Kd) {
    __shared__ unsigned short As[128 * 128];  // 32 KB
    __shared__ unsigned short Bs[64 * 128];   // 16 KB
    const int tid = threadIdx.x;
    const int wave = tid >> 6, lane = tid & 63;
    const int col = lane & 15, quad = lane >> 4;

    int p = blockIdx.x;                    // 768 blocks
    int xcd = p & 7, q = p >> 3;           // q in [0,96)
    int i_t = q % 16, jj = q / 16;         // jj in [0,6)
    const int m0 = i_t * 128, n0 = (jj * 8 + xcd) * 64;

    const int lrow = lane >> 4, lchk = lane & 15;
    int soffA[8], soffB[4];
    #pragma unroll
    for (int s = 0; s < 8; s++) {
        int r = wave * 32 + s * 4 + lrow;
        soffA[s] = r * Kd + ((lchk ^ (r & 7)) * 8);
    }
    #pragma unroll
    for (int s = 0; s < 4; s++) {
        int r = wave * 16 + s * 4 + lrow;
        soffB[s] = r * Kd + ((lchk ^ (r & 7)) * 8);
    }
    const unsigned short* Ab = A + (size_t)m0 * Kd;
    const unsigned short* Bb = BT + (size_t)n0 * Kd;

    f32x4 acc[2][4];
    #pragma unroll
    for (int i = 0; i < 2; i++)
        #pragma unroll
        for (int j = 0; j < 4; j++)
            acc[i][j] = (f32x4){0.f, 0.f, 0.f, 0.f};

    const int sw = col & 7;

    for (int k0 = 0; k0 < Kd; k0 += 128) {
        #pragma unroll
        for (int s = 0; s < 8; s++)
            gl_lds16(Ab + soffA[s] + k0, &As[(wave * 32 + s * 4) * 128]);
        #pragma unroll
        for (int s = 0; s < 4; s++)
            gl_lds16(Bb + soffB[s] + k0, &Bs[(wave * 16 + s * 4) * 128]);
        __syncthreads();

        #pragma unroll
        for (int kk = 0; kk < 4; kk++) {
            const int chko = ((kk * 4 + quad) ^ sw) * 8;
            bf16x8 af[2], bfr[4];
            #pragma unroll
            for (int i = 0; i < 2; i++)
                af[i] = *(const bf16x8*)&As[(wave * 32 + i * 16 + col) * 128 + chko];
            #pragma unroll
            for (int j = 0; j < 4; j++)
                bfr[j] = *(const bf16x8*)&Bs[(j * 16 + col) * 128 + chko];
            #pragma unroll
            for (int i = 0; i < 2; i++)
                #pragma unroll
                for (int j = 0; j < 4; j++)
                    acc[i][j] = __builtin_amdgcn_mfma_f32_16x16x32_bf16(af[i], bfr[j], acc[i][j], 0, 0, 0);
        }
        __syncthreads();
    }

    #pragma unroll
    for (int i = 0; i < 2; i++) {
        int row = m0 + wave * 32 + i * 16 + quad * 4;
        #pragma unroll
        for (int j = 0; j < 4; j++) {
            int c = n0 + j * 16 + col;
            #pragma unroll
            for (int r = 0; r < 4; r++)
                C[(size_t)(row + r) * N + c] = acc[i][j][r];
        }
    }
}

// ---------------- RMS-norm (+scale) + RoPE: 4 slots per block ----------------
__global__ __launch_bounds__(256) void k_norm_rope(const unsigned short* __restrict__ qkv,
                                                   const float2* __restrict__ trig,
                                                   const float* __restrict__ qscale,
                                                   const float* __restrict__ kscale,
                                                   unsigned short* __restrict__ qh,
                                                   unsigned short* __restrict__ kh,
                                                   unsigned short* __restrict__ vh) {
    const int t = blockIdx.x, y = blockIdx.y, h = threadIdx.x;
    __shared__ float wsum[4][4];
    __shared__ float ybuf[3][256];

    float val[4];
    #pragma unroll
    for (int g = 0; g < 4; g++)
        val[g] = bf2f(qkv[(size_t)t * QKV_COLS + (y + g * 8) * HD + h]);

    float ssg[4];
    #pragma unroll
    for (int g = 0; g < 4; g++) {
        float ss = val[g] * val[g];
        #pragma unroll
        for (int m = 1; m < 64; m <<= 1) ss += __shfl_xor(ss, m, 64);
        ssg[g] = ss;
    }
    if ((h & 63) == 0) {
        #pragma unroll
        for (int g = 0; g < 4; g++) wsum[g][h >> 6] = ssg[g];
    }
    __syncthreads();

    float2 sc = trig[(size_t)t * 128 + (h & 127)];
    float qs = 1.0f + qscale[h], ks = 1.0f + kscale[h];

    float yv[4];
    #pragma unroll
    for (int g = 0; g < 4; g++) {
        float tot = wsum[g][0] + wsum[g][1] + wsum[g][2] + wsum[g][3];
        float yy = val[g] * rsqrtf(tot * (1.0f / 256.0f) + 1e-6f);
        if (g < 2) yy *= qs;
        else if (g == 2) yy *= ks;
        yv[g] = yy;
        if (g < 3) ybuf[g][h] = yy;
    }
    __syncthreads();

    #pragma unroll
    for (int g = 0; g < 3; g++) {
        float other = ybuf[g][(h < 128) ? (h + 128) : (h - 128)];
        float outv = (h < 128) ? (yv[g] * sc.y - other * sc.x)
                               : (yv[g] * sc.y + other * sc.x);
        int slot = y + g * 8;
        if (slot < 16)
            qh[((size_t)slot * T_SEQ + t) * HD + h] = f2bf(outv);
        else
            kh[((size_t)(slot - 16) * T_SEQ + t) * HD + h] = f2bf(outv);
    }
    vh[((size_t)y * T_SEQ + t) * HD + h] = f2bf(yv[3]);
}

// ---------------- flash attention (32-s-tile, R3-proven) ----------------
__global__ __launch_bounds__(256) void k_attn(const unsigned short* __restrict__ qh,
                                              const unsigned short* __restrict__ kh,
                                              const unsigned short* __restrict__ vT,
                                              unsigned short* __restrict__ enc) {
    __shared__ unsigned short Ks[32 * 256];
    __shared__ unsigned short Vs[256 * 32];
    __shared__ unsigned short Pl[4][16 * 40];

    const int tid = threadIdx.x;
    const int wave = tid >> 6, lane = tid & 63;
    const int col = lane & 15, quad = lane >> 4;
    const int kk = blockIdx.x;
    const int t0b = blockIdx.y * 32;
    const int headSel = wave & 1, rowSel = wave >> 1;
    const int n = kk * 2 + headSel;
    const int tw = t0b + rowSel * 16;

    const unsigned short* qp = qh + ((size_t)n * T_SEQ + tw) * HD;
    const unsigned short* kp = kh + (size_t)kk * T_SEQ * HD;
    const unsigned short* vp = vT + (size_t)kk * HD * T_SEQ;

    bf16x8 qf[8];
    #pragma unroll
    for (int c = 0; c < 8; c++)
        qf[c] = *(const bf16x8*)(qp + (size_t)col * HD + c * 32 + quad * 8);

    int preK[4], preV[4], ldsKo[4], ldsVo[4];
    #pragma unroll
    for (int i = 0; i < 4; i++) {
        int krow = 2 * (wave * 4 + i) + (lane >> 5);
        int kpos = lane & 31;
        preK[i] = krow * HD + ((kpos ^ (krow & 7)) * 8);
        ldsKo[i] = (wave * 4 + i) * 512;
        int vh2 = (wave * 4 + i) * 16 + (lane >> 2);
        int vpp = lane & 3;
        preV[i] = vh2 * T_SEQ + ((vpp ^ (vh2 & 3)) * 8);
        ldsVo[i] = (wave * 4 + i) * 512;
    }

    f32x4 o[16];
    #pragma unroll
    for (int h = 0; h < 16; h++) o[h] = (f32x4){0.f, 0.f, 0.f, 0.f};
    float lsum[4] = {0.f, 0.f, 0.f, 0.f};

    int s_begin = t0b - (WINDOW - 1);
    if (s_begin < 0) s_begin = 0;
    s_begin &= ~31;
    const int s_end = t0b + 32;

    for (int s0 = s_begin; s0 < s_end; s0 += 32) {
        #pragma unroll
        for (int i = 0; i < 4; i++)
            gl_lds16(kp + (size_t)s0 * HD + preK[i], &Ks[ldsKo[i]]);
        #pragma unroll
        for (int i = 0; i < 4; i++)
            gl_lds16(vp + (size_t)s0 + preV[i], &Vs[ldsVo[i]]);
        __syncthreads();

        f32x4 S0 = (f32x4){0.f, 0.f, 0.f, 0.f};
        f32x4 S1 = (f32x4){0.f, 0.f, 0.f, 0.f};
        #pragma unroll
        for (int c = 0; c < 8; c++) {
            bf16x8 kf = *(const bf16x8*)&Ks[(size_t)col * HD + (((c * 4 + quad) ^ (col & 7)) * 8)];
            S0 = __builtin_amdgcn_mfma_f32_16x16x32_bf16(qf[c], kf, S0, 0, 0, 0);
        }
        #pragma unroll
        for (int c = 0; c < 8; c++) {
            bf16x8 kf = *(const bf16x8*)&Ks[(size_t)(16 + col) * HD + (((c * 4 + quad) ^ (col & 7)) * 8)];
            S1 = __builtin_amdgcn_mfma_f32_16x16x32_bf16(qf[c], kf, S1, 0, 0, 0);
        }

        #pragma unroll
        for (int r = 0; r < 4; r++) {
            int t = tw + quad * 4 + r;
            int sA = s0 + col, sB = sA + 16;
            bool vA = (sA <= t) && (sA >= t - (WINDOW - 1));
            bool vB = (sB <= t) && (sB >= t - (WINDOW - 1));
            float eA = __expf(S0[r] * (2.0f / SOFT_CAP));
            float eB = __expf(S1[r] * (2.0f / SOFT_CAP));
            float rA = __builtin_amdgcn_rcpf(eA + 1.0f);
            float rB = __builtin_amdgcn_rcpf(eB + 1.0f);
            float pA = __expf(SOFT_CAP - 2.0f * SOFT_CAP * rA);
            float pB = __expf(SOFT_CAP - 2.0f * SOFT_CAP * rB);
            pA = vA ? pA : 0.0f;
            pB = vB ? pB : 0.0f;
            lsum[r] += pA + pB;
            Pl[wave][(quad * 4 + r) * 40 + col] = f2bf(pA);
            Pl[wave][(quad * 4 + r) * 40 + 16 + col] = f2bf(pB);
        }

        bf16x8 pf = *(const bf16x8*)&Pl[wave][col * 40 + quad * 8];

        #pragma unroll
        for (int ht = 0; ht < 16; ht++) {
            int h = ht * 16 + col;
            bf16x8 vf = *(const bf16x8*)&Vs[(size_t)h * 32 + ((quad ^ (h & 3)) * 8)];
            o[ht] = __builtin_amdgcn_mfma_f32_16x16x32_bf16(pf, vf, o[ht], 0, 0, 0);
        }
        __syncthreads();
    }

    #pragma unroll
    for (int r = 0; r < 4; r++) {
        #pragma unroll
        for (int m = 1; m < 16; m <<= 1)
            lsum[r] += __shfl_xor(lsum[r], m, 16);
        lsum[r] = 1.0f / lsum[r];
    }
    #pragma unroll
    for (int ht = 0; ht < 16; ht++) {
        #pragma unroll
        for (int r = 0; r < 4; r++) {
            int t = tw + quad * 4 + r;
            enc[(size_t)t * (NQ * HD) + n * HD + ht * 16 + col] = f2bf(o[ht][r] * lsum[r]);
        }
    }
}

extern "C" void kernel_launch(void* const* d_in, const int* in_sizes, int n_in,
                              void* d_out, int out_size, void* d_ws, size_t ws_size,
                              hipStream_t stream) {
    const float* x       = (const float*)d_in[0];
    const int*   spos    = (const int*)d_in[1];
    const float* w_q     = (const float*)d_in[3];
    const float* w_kv    = (const float*)d_in[4];
    const float* w_out   = (const float*)d_in[5];
    const float* q_scale = (const float*)d_in[6];
    const float* k_scale = (const float*)d_in[7];
    float* out = (float*)d_out;

    char* ws = (char*)d_ws;
    unsigned short* xb     = (unsigned short*)(ws + 0);          // 2048x3072 bf16 (dead after gemm1)
    unsigned short* vh     = (unsigned short*)(ws + 0);          // 8x2048x256 bf16 (reuses xb[0:8.4MB])
    float2*         trig   = (float2*)(ws + 8388608);            // 2048x128 float2 (reuses xb tail)
    unsigned short* wT     = (unsigned short*)(ws + 12582912);   // 8192x3072 bf16
    unsigned short* wToutb = (unsigned short*)(ws + 12582912);   // 3072x4096 bf16 (reuse)
    unsigned short* encb   = (unsigned short*)(ws + 37748736);   // 2048x4096 bf16 (reuse)
    unsigned short* qkv    = (unsigned short*)(ws + 62914560);   // 2048x8192 bf16
    unsigned short* qh     = (unsigned short*)(ws + 96468992);   // 16x2048x256 bf16
    unsigned short* kh     = (unsigned short*)(ws + 113246208);  // 8x2048x256 bf16
    unsigned short* vT     = (unsigned short*)(ws + 121634816);  // 8x256x2048 bf16

    k_convert<<<dim3((T_SEQ * D_MODEL / 4 + 255) / 256), dim3(256), 0, stream>>>(
        x, xb, T_SEQ * D_MODEL / 4);
    k_transpose_bf16<<<dim3(HD / 32, D_MODEL / 32, NQ), dim3(32, 8), 0, stream>>>(
        w_q, wT, D_MODEL, HD);
    k_transpose_bf16<<<dim3(HD / 32, D_MODEL / 32, 16), dim3(32, 8), 0, stream>>>(
        w_kv, wT + (size_t)4096 * D_MODEL, D_MODEL, HD);
    k_gemm1<<<dim3((T_SEQ / 128) * (QKV_COLS / 256)), dim3(256), 0, stream>>>(
        xb, wT, qkv, T_SEQ, QKV_COLS, D_MODEL);
    k_trig<<<dim3(T_SEQ), dim3(128), 0, stream>>>(spos, trig);
    k_transpose_bf16<<<dim3(D_MODEL / 32, 4096 / 32, 1), dim3(32, 8), 0, stream>>>(
        w_out, wToutb, 4096, D_MODEL);
    k_norm_rope<<<dim3(T_SEQ, 8), dim3(256), 0, stream>>>(
        qkv, trig, q_scale, k_scale, qh, kh, vh);
    k_transpose_v<<<dim3(HD / 32, T_SEQ / 32, NKV), dim3(32, 8), 0, stream>>>(vh, vT);
    k_attn<<<dim3(NKV, T_SEQ / 32), dim3(256), 0, stream>>>(qh, kh, vT, encb);
    k_gemm2<<<dim3((T_SEQ / 128) * (D_MODEL / 64)), dim3(256), 0, stream>>>(
        encb, wToutb, out, T_SEQ, D_MODEL, NQ * HD);
}